// Round 10
// baseline (9655.809 us; speedup 1.0000x reference)
//
#include <hip/hip_runtime.h>
#include <hip/hip_bf16.h>
#include <math.h>

// ---------------------------------------------------------------------------
// CorrNet forward, MI355X. Round 10 (= round 8 resubmit; broker timeouts).
// Round-7 profile: k_amax = 622us/pass, MfmaUtil 13.5%, everything idle ->
// latency-bound (chained MFMAs, 2 waves/SIMD, per-tile barriers). Fix:
//   - B fragments loaded DIRECTLY from global (L2-resident, 4 MB) -- the
//     staged-LDS fragment equals the contiguous 16B chunk
//     bvh[(j0+ct*32+l31)*16 + ks*2+grp]. No LDS, no barriers.
//   - hi-only GEMM (1 MFMA vs 3): pass-2 exact fp32 verify makes approx
//     accuracy a margin question only. |err| <= 2^-8 -> AM_DELTA = 1e-2.
//   - 2 independent acc chains (ct=0/1), AM_CHUNKS=8 (chunk == XCD).
// Pipeline: k_init / k_mlp14 / k_mlp57 / k_amax<1> / k_amax<2> / k_oc
// ---------------------------------------------------------------------------

#define WPB 4        // waves per block for the MLP kernels
#define PB 8         // points per wave (weight-reuse batch)
#define MLP_GRID 512 // 512 blocks x 4 waves = 2048 waves = 16384/PB batches
#define AM_CHUNKS 8  // j-range split of the argmax GEMM (== XCD count)
#define AM_DELTA 1e-2f  // candidate margin (>= 2x the 2^-8 hi-only bound)

typedef unsigned short ushort_t;
typedef __attribute__((ext_vector_type(8))) short short8v;   // 8 bf16 = 4 VGPR
typedef __attribute__((ext_vector_type(16))) float f32x16;   // MFMA 32x32 acc

__device__ __forceinline__ float rsum32(float v) {
  v += __shfl_xor(v, 1);
  v += __shfl_xor(v, 2);
  v += __shfl_xor(v, 4);
  v += __shfl_xor(v, 8);
  v += __shfl_xor(v, 16);
  return v;
}
__device__ __forceinline__ float rsum64(float v) {
  v = rsum32(v);
  v += __shfl_xor(v, 32);
  return v;
}

// order-preserving float<->uint encoding (monotonic for all finite values)
__device__ __forceinline__ unsigned fenc(float f) {
  unsigned u = __float_as_uint(f);
  return (u & 0x80000000u) ? ~u : (u | 0x80000000u);
}
__device__ __forceinline__ float fdec(unsigned k) {
  return __uint_as_float((k & 0x80000000u) ? (k ^ 0x80000000u) : ~k);
}

// float -> bf16 bits (round-to-nearest-even)
__device__ __forceinline__ ushort_t f2bf(float f) {
  unsigned u = __float_as_uint(f);
  return (ushort_t)((u + 0x7FFFu + ((u >> 16) & 1u)) >> 16);
}

// exact fp32 dot (sequential adds) + packed (val,idx) atomicMax commit
__device__ __noinline__ void exact_commit(const float* __restrict__ a,
                                          const float* __restrict__ b,
                                          int j, unsigned long long* slot)
{
  const float4* a4 = (const float4*)a;
  const float4* b4 = (const float4*)b;
  float s = 0.f;
#pragma unroll 4
  for (int k = 0; k < 32; ++k) {
    float4 x = a4[k], y = b4[k];
    s += x.x * y.x; s += x.y * y.y; s += x.z * y.z; s += x.w * y.w;
  }
  unsigned long long pk = ((unsigned long long)fenc(s) << 32)
                        | (unsigned long long)(0xFFFFFFFFu - (unsigned)j);
  atomicMax(slot, pk);
}

// Batched Linear (x @ W.T + b) -> LeakyReLU(0.2) -> GroupNorm(32-ch groups).
// `in` = LDS [PB][IN_C]; lane owns channel lane (+64). Each weight float4 is
// loaded once and applied to PB points (LDS broadcast reads, conflict-free).
template<int OUT_C, int IN_C>
__device__ __forceinline__ void lin_gn_b(int lane,
    const float* __restrict__ W, const float* __restrict__ b,
    const float* __restrict__ gm, const float* __restrict__ be,
    const float* __restrict__ in, float (*out)[PB])
{
  constexpr int J = (OUT_C + 63) / 64;
  float acc[J][PB];
  const float4* w4[J];
#pragma unroll
  for (int j = 0; j < J; ++j) {
    w4[j] = reinterpret_cast<const float4*>(W + (size_t)(lane + 64 * j) * IN_C);
    const float bj = b[lane + 64 * j];
#pragma unroll
    for (int pb = 0; pb < PB; ++pb) acc[j][pb] = bj;
  }
#pragma unroll 2
  for (int k = 0; k < IN_C / 4; ++k) {
    float4 w[J];
#pragma unroll
    for (int j = 0; j < J; ++j) w[j] = w4[j][k];
#pragma unroll
    for (int pb = 0; pb < PB; ++pb) {
      float4 v = reinterpret_cast<const float4*>(in + pb * IN_C)[k];
#pragma unroll
      for (int j = 0; j < J; ++j)
        acc[j][pb] += w[j].x * v.x + w[j].y * v.y + w[j].z * v.z + w[j].w * v.w;
    }
  }
#pragma unroll
  for (int j = 0; j < J; ++j) {
    const int c = lane + 64 * j;
    const float gmc = gm[c], bec = be[c];
#pragma unroll
    for (int pb = 0; pb < PB; ++pb) {
      float a = acc[j][pb];
      a = a >= 0.f ? a : 0.2f * a;            // LeakyReLU(0.2)
      float s1 = rsum32(a);                    // group = 32 consecutive ch
      float s2 = rsum32(a * a);
      float mu = s1 * (1.f / 32.f);
      float var = s2 * (1.f / 32.f) - mu * mu;
      float r = rsqrtf(var + 1e-5f);
      out[j][pb] = (a - mu) * r * gmc + bec;
    }
  }
}

// -------------------------------- init -------------------------------------
__global__ void k_init(unsigned* __restrict__ gv, unsigned* __restrict__ gp,
                       unsigned long long* __restrict__ best,
                       unsigned* __restrict__ rmax, int n)
{
  int i = blockIdx.x * blockDim.x + threadIdx.x;
  if (i < 128) { gv[i] = 0u; gp[i] = 0u; }     // fenc floor (= -inf)
  for (int k = i; k < n; k += gridDim.x * blockDim.x) {
    best[k] = 0ull;
    rmax[k] = 0u;
  }
}

// ------------------------- layers 1-4 + col-max ----------------------------
__global__ __launch_bounds__(256) void k_mlp14(
    const float* __restrict__ x, int n,
    const float* __restrict__ W1, const float* __restrict__ b1, const float* __restrict__ g1, const float* __restrict__ be1,
    const float* __restrict__ W2, const float* __restrict__ b2, const float* __restrict__ g2, const float* __restrict__ be2,
    const float* __restrict__ W3, const float* __restrict__ b3, const float* __restrict__ g3, const float* __restrict__ be3,
    const float* __restrict__ W4, const float* __restrict__ b4, const float* __restrict__ g4, const float* __restrict__ be4,
    float* __restrict__ fOut, unsigned* __restrict__ gMax)
{
  __shared__ float xs[WPB][3 * PB];
  __shared__ float s32[WPB][PB][32];
  __shared__ float s64[WPB][PB][64];
  __shared__ float s128[WPB][PB][128];
  __shared__ float cms[WPB][128];
  const int wave = threadIdx.x >> 6, lane = threadIdx.x & 63;
  const int l31 = lane & 31, grp = lane >> 5;
  float cm0 = -3.4e38f, cm1 = -3.4e38f;
  const int gw = blockIdx.x * WPB + wave;
  const int nw = gridDim.x * WPB;
  const int nb = n / PB;                      // nb % nw == 0 -> uniform trips
  for (int bt = gw; bt < nb; bt += nw) {
    const int p0 = bt * PB;
    if (lane < 3 * PB) xs[wave][lane] = x[(size_t)p0 * 3 + lane];
    __syncthreads();
    // layer1: 3->32, one 32-ch group; two points per pass via half-waves
#pragma unroll
    for (int pb2 = 0; pb2 < PB; pb2 += 2) {
      const int pb = pb2 + grp;
      float a = b1[l31] + W1[l31 * 3] * xs[wave][3 * pb]
              + W1[l31 * 3 + 1] * xs[wave][3 * pb + 1]
              + W1[l31 * 3 + 2] * xs[wave][3 * pb + 2];
      a = a >= 0.f ? a : 0.2f * a;
      float s1 = rsum32(a), s2 = rsum32(a * a);   // half-wave-local groups
      float mu = s1 * (1.f / 32.f);
      float var = s2 * (1.f / 32.f) - mu * mu;
      float r = rsqrtf(var + 1e-5f);
      s32[wave][pb][l31] = (a - mu) * r * g1[l31] + be1[l31];
    }
    __syncthreads();
    float o1[1][PB];
    lin_gn_b<64, 32>(lane, W2, b2, g2, be2, &s32[wave][0][0], o1);
#pragma unroll
    for (int pb = 0; pb < PB; ++pb) s64[wave][pb][lane] = o1[0][pb];
    __syncthreads();
    float o2[2][PB];
    lin_gn_b<128, 64>(lane, W3, b3, g3, be3, &s64[wave][0][0], o2);
#pragma unroll
    for (int pb = 0; pb < PB; ++pb) {
      s128[wave][pb][lane] = o2[0][pb];
      s128[wave][pb][64 + lane] = o2[1][pb];
      fOut[(size_t)(p0 + pb) * 128 + lane] = o2[0][pb];
      fOut[(size_t)(p0 + pb) * 128 + 64 + lane] = o2[1][pb];
    }
    __syncthreads();
    float o3[2][PB];
    lin_gn_b<128, 128>(lane, W4, b4, g4, be4, &s128[wave][0][0], o3);
#pragma unroll
    for (int pb = 0; pb < PB; ++pb) {
      cm0 = fmaxf(cm0, o3[0][pb]);
      cm1 = fmaxf(cm1, o3[1][pb]);
    }
    __syncthreads();
  }
  cms[wave][lane] = cm0; cms[wave][64 + lane] = cm1;
  __syncthreads();
  if (threadIdx.x < 128) {
    float m0 = fmaxf(fmaxf(cms[0][threadIdx.x], cms[1][threadIdx.x]),
                     fmaxf(cms[2][threadIdx.x], cms[3][threadIdx.x]));
    atomicMax(&gMax[threadIdx.x], fenc(m0));
  }
}

// --------------------- layers 5-7 + row normalize + bf16 hi ----------------
__global__ __launch_bounds__(256) void k_mlp57(
    const float* __restrict__ f, const unsigned* __restrict__ gMax, int n,
    const float* __restrict__ W5, const float* __restrict__ b5, const float* __restrict__ g5, const float* __restrict__ be5,
    const float* __restrict__ W6, const float* __restrict__ b6, const float* __restrict__ g6, const float* __restrict__ be6,
    const float* __restrict__ W7, const float* __restrict__ b7,
    float* __restrict__ ovOut, ushort_t* __restrict__ ovH)
{
  __shared__ float Bin[WPB][PB][256];   // fg = [f | g]     (32 KB)
  __shared__ float C5[WPB][PB][128];    // h5               (16 KB)
  __shared__ float C6[WPB][PB][64];     // h6               (8 KB)
  const int wave = threadIdx.x >> 6, lane = threadIdx.x & 63;
  const float gv0 = fdec(gMax[lane]), gv1 = fdec(gMax[64 + lane]);
#pragma unroll
  for (int pb = 0; pb < PB; ++pb) {     // g half of fg: constant per launch
    Bin[wave][pb][128 + lane] = gv0;
    Bin[wave][pb][192 + lane] = gv1;
  }
  __syncthreads();
  const int gw = blockIdx.x * WPB + wave;
  const int nw = gridDim.x * WPB;
  const int nb = n / PB;
  for (int bt = gw; bt < nb; bt += nw) {
    const int p0 = bt * PB;
#pragma unroll
    for (int pb = 0; pb < PB; ++pb) {
      Bin[wave][pb][lane] = f[(size_t)(p0 + pb) * 128 + lane];
      Bin[wave][pb][64 + lane] = f[(size_t)(p0 + pb) * 128 + 64 + lane];
    }
    __syncthreads();
    float o5[2][PB];
    lin_gn_b<128, 256>(lane, W5, b5, g5, be5, &Bin[wave][0][0], o5);
#pragma unroll
    for (int pb = 0; pb < PB; ++pb) {
      C5[wave][pb][lane] = o5[0][pb];
      C5[wave][pb][64 + lane] = o5[1][pb];
    }
    __syncthreads();
    float o6[1][PB];
    lin_gn_b<64, 128>(lane, W6, b6, g6, be6, &C5[wave][0][0], o6);
#pragma unroll
    for (int pb = 0; pb < PB; ++pb) C6[wave][pb][lane] = o6[0][pb];
    __syncthreads();
    // layer7: plain linear 64->128, batched
    float acc0[PB], acc1[PB];
    {
      const float b70 = b7[lane], b71 = b7[64 + lane];
#pragma unroll
      for (int pb = 0; pb < PB; ++pb) { acc0[pb] = b70; acc1[pb] = b71; }
      const float4* w40 = reinterpret_cast<const float4*>(W7 + (size_t)lane * 64);
      const float4* w41 = reinterpret_cast<const float4*>(W7 + (size_t)(64 + lane) * 64);
#pragma unroll 2
      for (int k = 0; k < 16; ++k) {
        float4 wa = w40[k], wb = w41[k];
#pragma unroll
        for (int pb = 0; pb < PB; ++pb) {
          float4 v = reinterpret_cast<const float4*>(&C6[wave][pb][0])[k];
          acc0[pb] += wa.x * v.x + wa.y * v.y + wa.z * v.z + wa.w * v.w;
          acc1[pb] += wb.x * v.x + wb.y * v.y + wb.z * v.z + wb.w * v.w;
        }
      }
    }
#pragma unroll
    for (int pb = 0; pb < PB; ++pb) {
      float ss = rsum64(acc0[pb] * acc0[pb] + acc1[pb] * acc1[pb]);
      float inv = 1.0f / sqrtf(ss);
      float v0 = acc0[pb] * inv, v1 = acc1[pb] * inv;
      const size_t o = (size_t)(p0 + pb) * 128;
      ovOut[o + lane] = v0;
      ovOut[o + 64 + lane] = v1;
      ovH[o + lane] = f2bf(v0);
      ovH[o + 64 + lane] = f2bf(v1);
    }
    __syncthreads();
  }
}

// ---------------- two-phase fused ov@op.T + row argmax (MFMA) --------------
// Barrier-free: each lane's B fragment is the contiguous global 16B chunk
// bvh[(j0+ct*32+l31)*16 + ks*2+grp] (identical layout to the old LDS stage).
// hi-only GEMM; |approx - exact| <= 2^-8 (unit vectors) << AM_DELTA.
// PASS 1: per-row approx max -> rowmax (fenc atomicMax).
// PASS 2: entries with c >= rowmax - AM_DELTA -> exact fp32 re-eval +
//         packed (fenc(exact)<<32 | ~idx) atomicMax -> fp32-argmax semantics.
// C layout (verified): col = lane&31, row = (reg&3)+8*(reg>>2)+4*(lane>>5).
template<int PASS>
__global__ __launch_bounds__(256) void k_amax(
    const ushort_t* __restrict__ avh, const ushort_t* __restrict__ bvh,
    const float* __restrict__ ovf, const float* __restrict__ opf,
    int m, unsigned* __restrict__ rowmax, unsigned long long* __restrict__ best)
{
  const int tid = threadIdx.x;
  const int wave = tid >> 6, lane = tid & 63;
  const int l31 = lane & 31, grp = lane >> 5;
  const int rowBlock = blockIdx.x / AM_CHUNKS;
  const int chunk = blockIdx.x % AM_CHUNKS;   // == XCD id under round-robin
  const int row0 = rowBlock * 128;
  const int jspan = m / AM_CHUNKS;
  const int j0beg = chunk * jspan;
  const int iters = jspan / 64;

  // ---- A fragments, once per block: row = row0 + wave*32 + (lane&31) ----
  const int myrow = row0 + wave * 32 + l31;
  short8v ah[8];
  {
    const short8v* rh = (const short8v*)(avh + (size_t)myrow * 128);
#pragma unroll
    for (int ks = 0; ks < 8; ++ks) ah[ks] = rh[ks * 2 + grp];
  }

  // pass-1 state: running per-row approx max.  pass-2 state: thresholds.
  float rmx[16];
  float thr[16];
#pragma unroll
  for (int r = 0; r < 16; ++r) {
    if constexpr (PASS == 1) {
      rmx[r] = -3.4e38f;
    } else {
      const int row = row0 + wave * 32 + (r & 3) + 8 * (r >> 2) + 4 * grp;
      thr[r] = fdec(rowmax[row]) - AM_DELTA;   // wave-uniform, broadcast
    }
  }

  const short8v* B = (const short8v*)bvh;
  for (int it = 0; it < iters; ++it) {
    const int j0 = j0beg + it * 64;
    // per-lane fragment bases for the two 32-column sub-tiles
    const short8v* Bc0 = B + (size_t)(j0 + l31) * 16 + grp;
    const short8v* Bc1 = B + (size_t)(j0 + 32 + l31) * 16 + grp;
    f32x16 c0 = {}, c1 = {};
#pragma unroll
    for (int ks = 0; ks < 8; ++ks) {           // two independent acc chains
      short8v b0 = Bc0[ks * 2];
      short8v b1 = Bc1[ks * 2];
      c0 = __builtin_amdgcn_mfma_f32_32x32x16_bf16(ah[ks], b0, c0, 0, 0, 0);
      c1 = __builtin_amdgcn_mfma_f32_32x32x16_bf16(ah[ks], b1, c1, 0, 0, 0);
    }
    if constexpr (PASS == 1) {
#pragma unroll
      for (int r = 0; r < 16; ++r)
        rmx[r] = fmaxf(rmx[r], fmaxf(c0[r], c1[r]));
    } else {
      bool any = false;
#pragma unroll
      for (int r = 0; r < 16; ++r)
        any = any || (c0[r] >= thr[r]) || (c1[r] >= thr[r]);
      if (__any((int)any)) {                   // rare: exact re-eval path
#pragma unroll
        for (int r = 0; r < 16; ++r) {
          const int row = row0 + wave * 32 + (r & 3) + 8 * (r >> 2) + 4 * grp;
          if (c0[r] >= thr[r])
            exact_commit(ovf + (size_t)row * 128,
                         opf + (size_t)(j0 + l31) * 128, j0 + l31, &best[row]);
          if (c1[r] >= thr[r])
            exact_commit(ovf + (size_t)row * 128,
                         opf + (size_t)(j0 + 32 + l31) * 128, j0 + 32 + l31,
                         &best[row]);
        }
      }
    }
  }

  if constexpr (PASS == 1) {
    // butterfly fmax across the 32 column-lanes, then one atomic per row
#pragma unroll
    for (int mm = 1; mm <= 16; mm <<= 1) {
#pragma unroll
      for (int r = 0; r < 16; ++r) rmx[r] = fmaxf(rmx[r], __shfl_xor(rmx[r], mm));
    }
    if (l31 == 0) {
#pragma unroll
      for (int r = 0; r < 16; ++r) {
        const int row = row0 + wave * 32 + (r & 3) + 8 * (r >> 2) + 4 * grp;
        atomicMax(&rowmax[row], fenc(rmx[r]));
      }
    }
  }
}

// ----------------------- gather + layer8 + W9 (batched) --------------------
__global__ __launch_bounds__(256) void k_oc(
    const float* __restrict__ ovn, const float* __restrict__ opn,
    const unsigned long long* __restrict__ best, int n,
    const float* __restrict__ W8, const float* __restrict__ b8,
    const float* __restrict__ g8, const float* __restrict__ be8,
    const float* __restrict__ W9, const float* __restrict__ b9,
    float* __restrict__ oc)
{
  __shared__ float Y[WPB][PB][260];     // YXS rows (33.3 KB)
  const int wave = threadIdx.x >> 6, lane = threadIdx.x & 63;
  const int gw = blockIdx.x * WPB + wave;
  const int nw = gridDim.x * WPB;
  const int nb = n / PB;
  const float w9l = W9[lane], b90 = b9[0];
  const float b8l = b8[lane], g8l = g8[lane], be8l = be8[lane];
  const float* w = W8 + (size_t)lane * 257;
  for (int bt = gw; bt < nb; bt += nw) {
    const int p0 = bt * PB;
#pragma unroll
    for (int pb = 0; pb < PB; ++pb) {
      const int p = p0 + pb;
      unsigned long long v = best[p];
      int j = (int)(0xFFFFFFFFu - (unsigned)(v & 0xFFFFFFFFu));
      float Sv = fdec((unsigned)(v >> 32));
      Y[wave][pb][lane]       = ovn[(size_t)p * 128 + lane];
      Y[wave][pb][64 + lane]  = ovn[(size_t)p * 128 + 64 + lane];
      Y[wave][pb][128 + lane] = opn[(size_t)j * 128 + lane];
      Y[wave][pb][192 + lane] = opn[(size_t)j * 128 + 64 + lane];
      if (lane == 0) Y[wave][pb][256] = Sv;
    }
    __syncthreads();
    // layer8: 257 -> 64, batched over PB points; W8 rows are 257-strided
    // (1028 B, not 16B-aligned) -> scalar weight loads, float4 LDS reads.
    float acc[PB];
#pragma unroll
    for (int pb = 0; pb < PB; ++pb) acc[pb] = b8l;
#pragma unroll 2
    for (int k4 = 0; k4 < 64; ++k4) {
      const float w0 = w[k4 * 4], w1 = w[k4 * 4 + 1];
      const float w2 = w[k4 * 4 + 2], w3 = w[k4 * 4 + 3];
#pragma unroll
      for (int pb = 0; pb < PB; ++pb) {
        float4 v = reinterpret_cast<const float4*>(&Y[wave][pb][0])[k4];
        acc[pb] += w0 * v.x + w1 * v.y + w2 * v.z + w3 * v.w;
      }
    }
    {
      const float w256 = w[256];
#pragma unroll
      for (int pb = 0; pb < PB; ++pb) acc[pb] += w256 * Y[wave][pb][256];
    }
#pragma unroll
    for (int pb = 0; pb < PB; ++pb) {
      float a = acc[pb];
      a = a >= 0.f ? a : 0.2f * a;
      float s1 = rsum32(a), s2 = rsum32(a * a);
      float mu = s1 * (1.f / 32.f);
      float var = s2 * (1.f / 32.f) - mu * mu;
      float r = rsqrtf(var + 1e-5f);
      float y = (a - mu) * r * g8l + be8l;
      float tot = rsum64(y * w9l);
      if (lane == 0) oc[p0 + pb] = tot + b90;
    }
    __syncthreads();
  }
}

// ---------------------------------------------------------------------------
extern "C" void kernel_launch(void* const* d_in, const int* in_sizes, int n_in,
                              void* d_out, int out_size, void* d_ws, size_t ws_size,
                              hipStream_t stream)
{
  (void)n_in; (void)out_size; (void)ws_size;
  const float* vtx = (const float*)d_in[0];
  const float* pts = (const float*)d_in[1];
  const float* W1 = (const float*)d_in[2];  const float* b1 = (const float*)d_in[3];
  const float* g1 = (const float*)d_in[4];  const float* be1 = (const float*)d_in[5];
  const float* W2 = (const float*)d_in[6];  const float* b2 = (const float*)d_in[7];
  const float* g2 = (const float*)d_in[8];  const float* be2 = (const float*)d_in[9];
  const float* W3 = (const float*)d_in[10]; const float* b3 = (const float*)d_in[11];
  const float* g3 = (const float*)d_in[12]; const float* be3 = (const float*)d_in[13];
  const float* W4 = (const float*)d_in[14]; const float* b4 = (const float*)d_in[15];
  const float* g4 = (const float*)d_in[16]; const float* be4 = (const float*)d_in[17];
  const float* W5 = (const float*)d_in[18]; const float* b5 = (const float*)d_in[19];
  const float* g5 = (const float*)d_in[20]; const float* be5 = (const float*)d_in[21];
  const float* W6 = (const float*)d_in[22]; const float* b6 = (const float*)d_in[23];
  const float* g6 = (const float*)d_in[24]; const float* be6 = (const float*)d_in[25];
  const float* W7 = (const float*)d_in[26]; const float* b7 = (const float*)d_in[27];
  const float* W8 = (const float*)d_in[28]; const float* b8 = (const float*)d_in[29];
  const float* g8 = (const float*)d_in[30]; const float* be8 = (const float*)d_in[31];
  const float* W9 = (const float*)d_in[32]; const float* b9 = (const float*)d_in[33];

  const int n = in_sizes[0] / 3;   // 16384
  const int m = in_sizes[1] / 3;   // 16384

  // ---- workspace layout (bytes) ----
  // f_v @ 0 (n*128*4); f_p @ f_v_end (m*128*4; ovh aliases it once consumed)
  // oph @ f_p_end (m*128*2); then g_v/g_p, best[n] u64, rmax[n] u32
  char* wsb = (char*)d_ws;
  float* f_v = (float*)wsb;
  size_t f_v_bytes = (size_t)n * 128 * 4;
  float* f_p = (float*)(wsb + f_v_bytes);
  size_t f_p_bytes = (size_t)m * 128 * 4;
  ushort_t* ovh = (ushort_t*)(wsb + f_v_bytes);          // alias f_p
  ushort_t* oph = (ushort_t*)(wsb + f_v_bytes + f_p_bytes);
  char* tail = wsb + f_v_bytes + f_p_bytes + (size_t)m * 128 * 2;
  unsigned* g_v = (unsigned*)tail;
  unsigned* g_p = g_v + 128;
  unsigned long long* best = (unsigned long long*)(g_p + 128);  // 8B aligned
  unsigned* rmaxv = (unsigned*)(best + n);

  float* out_ov = (float*)d_out;                 // n*128
  float* out_op = out_ov + (size_t)n * 128;      // m*128
  float* out_oc = out_op + (size_t)m * 128;      // n

  k_init<<<64, 256, 0, stream>>>(g_v, g_p, best, rmaxv, n);

  k_mlp14<<<MLP_GRID, 256, 0, stream>>>(vtx, n, W1, b1, g1, be1, W2, b2, g2, be2,
                                        W3, b3, g3, be3, W4, b4, g4, be4, f_v, g_v);
  k_mlp14<<<MLP_GRID, 256, 0, stream>>>(pts, m, W1, b1, g1, be1, W2, b2, g2, be2,
                                        W3, b3, g3, be3, W4, b4, g4, be4, f_p, g_p);

  // pts pass FIRST (f_p consumed), then vtx pass may overwrite f_p with ovh
  k_mlp57<<<MLP_GRID, 256, 0, stream>>>(f_p, g_p, m, W5, b5, g5, be5,
                                        W6, b6, g6, be6, W7, b7, out_op, oph);
  k_mlp57<<<MLP_GRID, 256, 0, stream>>>(f_v, g_v, n, W5, b5, g5, be5,
                                        W6, b6, g6, be6, W7, b7, out_ov, ovh);

  const int am_grid = (n / 128) * AM_CHUNKS;
  k_amax<1><<<am_grid, 256, 0, stream>>>(ovh, oph, out_ov, out_op,
                                         m, rmaxv, best);
  k_amax<2><<<am_grid, 256, 0, stream>>>(ovh, oph, out_ov, out_op,
                                         m, rmaxv, best);

  k_oc<<<MLP_GRID, 256, 0, stream>>>(out_ov, out_op, best, n,
                                     W8, b8, g8, be8, W9, b9, out_oc);
}

// Round 11
// 1193.859 us; speedup vs baseline: 8.0879x; 8.0879x over previous
//
#include <hip/hip_runtime.h>
#include <hip/hip_bf16.h>
#include <math.h>

// ---------------------------------------------------------------------------
// CorrNet forward, MI355X. Round 11: round-7 k_amax + 4 independent MFMA
// accumulator chains (hh/cross per ct), AM_CHUNKS=8. Round-10's direct-global
// loads (256B-stride/lane, uncoalesced) and delta=1e-2 (commit storm) both
// regressed badly -> reverted to the proven staged/3-term/2e-4 structure.
// Pipeline: k_init / k_mlp14 / k_mlp57 / k_amax<1> / k_amax<2> / k_oc
// ---------------------------------------------------------------------------

#define WPB 4        // waves per block for the MLP kernels
#define PB 8         // points per wave (weight-reuse batch)
#define MLP_GRID 512 // 512 blocks x 4 waves = 2048 waves = 16384/PB batches
#define AM_CHUNKS 8  // j-range split of the argmax GEMM
#define AM_DELTA 2e-4f  // candidate margin (>> 3-term error bound ~4e-6)

typedef unsigned short ushort_t;
typedef __attribute__((ext_vector_type(8))) short short8v;   // 8 bf16 = 4 VGPR
typedef __attribute__((ext_vector_type(16))) float f32x16;   // MFMA 32x32 acc

__device__ __forceinline__ float rsum32(float v) {
  v += __shfl_xor(v, 1);
  v += __shfl_xor(v, 2);
  v += __shfl_xor(v, 4);
  v += __shfl_xor(v, 8);
  v += __shfl_xor(v, 16);
  return v;
}
__device__ __forceinline__ float rsum64(float v) {
  v = rsum32(v);
  v += __shfl_xor(v, 32);
  return v;
}

// order-preserving float<->uint encoding (monotonic for all finite values)
__device__ __forceinline__ unsigned fenc(float f) {
  unsigned u = __float_as_uint(f);
  return (u & 0x80000000u) ? ~u : (u | 0x80000000u);
}
__device__ __forceinline__ float fdec(unsigned k) {
  return __uint_as_float((k & 0x80000000u) ? (k ^ 0x80000000u) : ~k);
}

// float -> bf16 bits (round-to-nearest-even), and back
__device__ __forceinline__ ushort_t f2bf(float f) {
  unsigned u = __float_as_uint(f);
  return (ushort_t)((u + 0x7FFFu + ((u >> 16) & 1u)) >> 16);
}
__device__ __forceinline__ float bf2f(ushort_t h) {
  return __uint_as_float(((unsigned)h) << 16);
}

// exact fp32 dot (sequential adds) + packed (val,idx) atomicMax commit
__device__ __noinline__ void exact_commit(const float* __restrict__ a,
                                          const float* __restrict__ b,
                                          int j, unsigned long long* slot)
{
  const float4* a4 = (const float4*)a;
  const float4* b4 = (const float4*)b;
  float s = 0.f;
#pragma unroll 4
  for (int k = 0; k < 32; ++k) {
    float4 x = a4[k], y = b4[k];
    s += x.x * y.x; s += x.y * y.y; s += x.z * y.z; s += x.w * y.w;
  }
  unsigned long long pk = ((unsigned long long)fenc(s) << 32)
                        | (unsigned long long)(0xFFFFFFFFu - (unsigned)j);
  atomicMax(slot, pk);
}

// Batched Linear (x @ W.T + b) -> LeakyReLU(0.2) -> GroupNorm(32-ch groups).
template<int OUT_C, int IN_C>
__device__ __forceinline__ void lin_gn_b(int lane,
    const float* __restrict__ W, const float* __restrict__ b,
    const float* __restrict__ gm, const float* __restrict__ be,
    const float* __restrict__ in, float (*out)[PB])
{
  constexpr int J = (OUT_C + 63) / 64;
  float acc[J][PB];
  const float4* w4[J];
#pragma unroll
  for (int j = 0; j < J; ++j) {
    w4[j] = reinterpret_cast<const float4*>(W + (size_t)(lane + 64 * j) * IN_C);
    const float bj = b[lane + 64 * j];
#pragma unroll
    for (int pb = 0; pb < PB; ++pb) acc[j][pb] = bj;
  }
#pragma unroll 2
  for (int k = 0; k < IN_C / 4; ++k) {
    float4 w[J];
#pragma unroll
    for (int j = 0; j < J; ++j) w[j] = w4[j][k];
#pragma unroll
    for (int pb = 0; pb < PB; ++pb) {
      float4 v = reinterpret_cast<const float4*>(in + pb * IN_C)[k];
#pragma unroll
      for (int j = 0; j < J; ++j)
        acc[j][pb] += w[j].x * v.x + w[j].y * v.y + w[j].z * v.z + w[j].w * v.w;
    }
  }
#pragma unroll
  for (int j = 0; j < J; ++j) {
    const int c = lane + 64 * j;
    const float gmc = gm[c], bec = be[c];
#pragma unroll
    for (int pb = 0; pb < PB; ++pb) {
      float a = acc[j][pb];
      a = a >= 0.f ? a : 0.2f * a;            // LeakyReLU(0.2)
      float s1 = rsum32(a);                    // group = 32 consecutive ch
      float s2 = rsum32(a * a);
      float mu = s1 * (1.f / 32.f);
      float var = s2 * (1.f / 32.f) - mu * mu;
      float r = rsqrtf(var + 1e-5f);
      out[j][pb] = (a - mu) * r * gmc + bec;
    }
  }
}

// -------------------------------- init -------------------------------------
__global__ void k_init(unsigned* __restrict__ gv, unsigned* __restrict__ gp,
                       unsigned long long* __restrict__ best,
                       unsigned* __restrict__ rmax, int n)
{
  int i = blockIdx.x * blockDim.x + threadIdx.x;
  if (i < 128) { gv[i] = 0u; gp[i] = 0u; }     // fenc floor (= -inf)
  for (int k = i; k < n; k += gridDim.x * blockDim.x) {
    best[k] = 0ull;
    rmax[k] = 0u;
  }
}

// ------------------------- layers 1-4 + col-max ----------------------------
__global__ __launch_bounds__(256) void k_mlp14(
    const float* __restrict__ x, int n,
    const float* __restrict__ W1, const float* __restrict__ b1, const float* __restrict__ g1, const float* __restrict__ be1,
    const float* __restrict__ W2, const float* __restrict__ b2, const float* __restrict__ g2, const float* __restrict__ be2,
    const float* __restrict__ W3, const float* __restrict__ b3, const float* __restrict__ g3, const float* __restrict__ be3,
    const float* __restrict__ W4, const float* __restrict__ b4, const float* __restrict__ g4, const float* __restrict__ be4,
    float* __restrict__ fOut, unsigned* __restrict__ gMax)
{
  __shared__ float xs[WPB][3 * PB];
  __shared__ float s32[WPB][PB][32];
  __shared__ float s64[WPB][PB][64];
  __shared__ float s128[WPB][PB][128];
  __shared__ float cms[WPB][128];
  const int wave = threadIdx.x >> 6, lane = threadIdx.x & 63;
  const int l31 = lane & 31, grp = lane >> 5;
  float cm0 = -3.4e38f, cm1 = -3.4e38f;
  const int gw = blockIdx.x * WPB + wave;
  const int nw = gridDim.x * WPB;
  const int nb = n / PB;                      // nb % nw == 0 -> uniform trips
  for (int bt = gw; bt < nb; bt += nw) {
    const int p0 = bt * PB;
    if (lane < 3 * PB) xs[wave][lane] = x[(size_t)p0 * 3 + lane];
    __syncthreads();
    // layer1: 3->32, one 32-ch group; two points per pass via half-waves
#pragma unroll
    for (int pb2 = 0; pb2 < PB; pb2 += 2) {
      const int pb = pb2 + grp;
      float a = b1[l31] + W1[l31 * 3] * xs[wave][3 * pb]
              + W1[l31 * 3 + 1] * xs[wave][3 * pb + 1]
              + W1[l31 * 3 + 2] * xs[wave][3 * pb + 2];
      a = a >= 0.f ? a : 0.2f * a;
      float s1 = rsum32(a), s2 = rsum32(a * a);   // half-wave-local groups
      float mu = s1 * (1.f / 32.f);
      float var = s2 * (1.f / 32.f) - mu * mu;
      float r = rsqrtf(var + 1e-5f);
      s32[wave][pb][l31] = (a - mu) * r * g1[l31] + be1[l31];
    }
    __syncthreads();
    float o1[1][PB];
    lin_gn_b<64, 32>(lane, W2, b2, g2, be2, &s32[wave][0][0], o1);
#pragma unroll
    for (int pb = 0; pb < PB; ++pb) s64[wave][pb][lane] = o1[0][pb];
    __syncthreads();
    float o2[2][PB];
    lin_gn_b<128, 64>(lane, W3, b3, g3, be3, &s64[wave][0][0], o2);
#pragma unroll
    for (int pb = 0; pb < PB; ++pb) {
      s128[wave][pb][lane] = o2[0][pb];
      s128[wave][pb][64 + lane] = o2[1][pb];
      fOut[(size_t)(p0 + pb) * 128 + lane] = o2[0][pb];
      fOut[(size_t)(p0 + pb) * 128 + 64 + lane] = o2[1][pb];
    }
    __syncthreads();
    float o3[2][PB];
    lin_gn_b<128, 128>(lane, W4, b4, g4, be4, &s128[wave][0][0], o3);
#pragma unroll
    for (int pb = 0; pb < PB; ++pb) {
      cm0 = fmaxf(cm0, o3[0][pb]);
      cm1 = fmaxf(cm1, o3[1][pb]);
    }
    __syncthreads();
  }
  cms[wave][lane] = cm0; cms[wave][64 + lane] = cm1;
  __syncthreads();
  if (threadIdx.x < 128) {
    float m0 = fmaxf(fmaxf(cms[0][threadIdx.x], cms[1][threadIdx.x]),
                     fmaxf(cms[2][threadIdx.x], cms[3][threadIdx.x]));
    atomicMax(&gMax[threadIdx.x], fenc(m0));
  }
}

// --------------------- layers 5-7 + row normalize + bf16 split -------------
__global__ __launch_bounds__(256) void k_mlp57(
    const float* __restrict__ f, const unsigned* __restrict__ gMax, int n,
    const float* __restrict__ W5, const float* __restrict__ b5, const float* __restrict__ g5, const float* __restrict__ be5,
    const float* __restrict__ W6, const float* __restrict__ b6, const float* __restrict__ g6, const float* __restrict__ be6,
    const float* __restrict__ W7, const float* __restrict__ b7,
    float* __restrict__ ovOut,
    ushort_t* __restrict__ ovH, ushort_t* __restrict__ ovL)
{
  __shared__ float Bin[WPB][PB][256];   // fg = [f | g]     (32 KB)
  __shared__ float C5[WPB][PB][128];    // h5               (16 KB)
  __shared__ float C6[WPB][PB][64];     // h6               (8 KB)
  const int wave = threadIdx.x >> 6, lane = threadIdx.x & 63;
  const float gv0 = fdec(gMax[lane]), gv1 = fdec(gMax[64 + lane]);
#pragma unroll
  for (int pb = 0; pb < PB; ++pb) {     // g half of fg: constant per launch
    Bin[wave][pb][128 + lane] = gv0;
    Bin[wave][pb][192 + lane] = gv1;
  }
  __syncthreads();
  const int gw = blockIdx.x * WPB + wave;
  const int nw = gridDim.x * WPB;
  const int nb = n / PB;
  for (int bt = gw; bt < nb; bt += nw) {
    const int p0 = bt * PB;
#pragma unroll
    for (int pb = 0; pb < PB; ++pb) {
      Bin[wave][pb][lane] = f[(size_t)(p0 + pb) * 128 + lane];
      Bin[wave][pb][64 + lane] = f[(size_t)(p0 + pb) * 128 + 64 + lane];
    }
    __syncthreads();
    float o5[2][PB];
    lin_gn_b<128, 256>(lane, W5, b5, g5, be5, &Bin[wave][0][0], o5);
#pragma unroll
    for (int pb = 0; pb < PB; ++pb) {
      C5[wave][pb][lane] = o5[0][pb];
      C5[wave][pb][64 + lane] = o5[1][pb];
    }
    __syncthreads();
    float o6[1][PB];
    lin_gn_b<64, 128>(lane, W6, b6, g6, be6, &C5[wave][0][0], o6);
#pragma unroll
    for (int pb = 0; pb < PB; ++pb) C6[wave][pb][lane] = o6[0][pb];
    __syncthreads();
    // layer7: plain linear 64->128, batched
    float acc0[PB], acc1[PB];
    {
      const float b70 = b7[lane], b71 = b7[64 + lane];
#pragma unroll
      for (int pb = 0; pb < PB; ++pb) { acc0[pb] = b70; acc1[pb] = b71; }
      const float4* w40 = reinterpret_cast<const float4*>(W7 + (size_t)lane * 64);
      const float4* w41 = reinterpret_cast<const float4*>(W7 + (size_t)(64 + lane) * 64);
#pragma unroll 2
      for (int k = 0; k < 16; ++k) {
        float4 wa = w40[k], wb = w41[k];
#pragma unroll
        for (int pb = 0; pb < PB; ++pb) {
          float4 v = reinterpret_cast<const float4*>(&C6[wave][pb][0])[k];
          acc0[pb] += wa.x * v.x + wa.y * v.y + wa.z * v.z + wa.w * v.w;
          acc1[pb] += wb.x * v.x + wb.y * v.y + wb.z * v.z + wb.w * v.w;
        }
      }
    }
#pragma unroll
    for (int pb = 0; pb < PB; ++pb) {
      float ss = rsum64(acc0[pb] * acc0[pb] + acc1[pb] * acc1[pb]);
      float inv = 1.0f / sqrtf(ss);
      float v0 = acc0[pb] * inv, v1 = acc1[pb] * inv;
      const size_t o = (size_t)(p0 + pb) * 128;
      ovOut[o + lane] = v0;
      ovOut[o + 64 + lane] = v1;
      ushort_t h0 = f2bf(v0), h1 = f2bf(v1);
      ovH[o + lane] = h0;
      ovH[o + 64 + lane] = h1;
      ovL[o + lane] = f2bf(v0 - bf2f(h0));
      ovL[o + 64 + lane] = f2bf(v1 - bf2f(h1));
    }
    __syncthreads();
  }
}

// ---------------- two-phase fused ov@op.T + row argmax (MFMA) --------------
// Round-7 proven structure (coalesced LDS staging, 65-pad, reg prefetch,
// 3-term split s = hh + hl + lh, delta 2e-4) with ONE change: the MFMA
// accumulation is split into 4 INDEPENDENT chains (hh & cross, per ct) so
// the matrix pipe is not serialized on one accumulator's dependency chain.
// C layout (verified): col = lane&31, row = (reg&3)+8*(reg>>2)+4*(lane>>5).
template<int PASS>
__global__ __launch_bounds__(256) void k_amax(
    const ushort_t* __restrict__ avh, const ushort_t* __restrict__ avl,
    const ushort_t* __restrict__ bvh, const ushort_t* __restrict__ bvl,
    const float* __restrict__ ovf, const float* __restrict__ opf,
    int m, unsigned* __restrict__ rowmax, unsigned long long* __restrict__ best)
{
  // [hi/lo][k-chunk 16][col pad 65][8 bf16] = 32.5 KB; 16B-aligned for b128
  __shared__ __align__(16) short lbuf[2][16][65][8];
  const int tid = threadIdx.x;
  const int wave = tid >> 6, lane = tid & 63;
  const int l31 = lane & 31, grp = lane >> 5;
  const int rowBlock = blockIdx.x / AM_CHUNKS;
  const int chunk = blockIdx.x % AM_CHUNKS;
  const int row0 = rowBlock * 128;
  const int jspan = m / AM_CHUNKS;
  const int j0beg = chunk * jspan;
  const int iters = jspan / 64;

  // ---- A fragments, once per block: row = row0 + wave*32 + (lane&31) ----
  const int myrow = row0 + wave * 32 + l31;
  short8v ah[8], al[8];
  {
    const short8v* rh = (const short8v*)(avh + (size_t)myrow * 128);
    const short8v* rl = (const short8v*)(avl + (size_t)myrow * 128);
#pragma unroll
    for (int ks = 0; ks < 8; ++ks) {
      ah[ks] = rh[ks * 2 + grp];        // k = ks*16 + grp*8 + [0..7]
      al[ks] = rl[ks * 2 + grp];
    }
  }

  // staging mapping: thread t loads row j0+(t>>4)+16i, bytes (t&15)*16 (coalesced)
  const int sks = tid & 15;
  const int scol0 = tid >> 4;
  // per-lane LDS fragment base, in 16B units: [grp][l31]
  const short8v* fragH = (const short8v*)&lbuf[0][grp][l31][0];
  const short8v* fragL = (const short8v*)&lbuf[1][grp][l31][0];

  // pass-1 state: running per-row approx max.  pass-2 state: thresholds.
  float rmx[16];
  float thr[16];
#pragma unroll
  for (int r = 0; r < 16; ++r) {
    if constexpr (PASS == 1) {
      rmx[r] = -3.4e38f;
    } else {
      const int row = row0 + wave * 32 + (r & 3) + 8 * (r >> 2) + 4 * grp;
      thr[r] = fdec(rowmax[row]) - AM_DELTA;   // wave-uniform load, broadcast
    }
  }

  // prologue loads (tile 0)
  short8v ph[4], pl[4];
#pragma unroll
  for (int i = 0; i < 4; ++i) {
    int col = scol0 + 16 * i;
    ph[i] = ((const short8v*)bvh)[(size_t)(j0beg + col) * 16 + sks];
    pl[i] = ((const short8v*)bvl)[(size_t)(j0beg + col) * 16 + sks];
  }

  for (int it = 0; it < iters; ++it) {
    __syncthreads();                               // LDS free (prev tile consumed)
#pragma unroll
    for (int i = 0; i < 4; ++i) {
      int col = scol0 + 16 * i;
      *(short8v*)&lbuf[0][sks][col][0] = ph[i];
      *(short8v*)&lbuf[1][sks][col][0] = pl[i];
    }
    __syncthreads();
    if (it + 1 < iters) {                          // prefetch next tile -> regs,
      int j0n = j0beg + (it + 1) * 64;             // overlaps with MFMA below
#pragma unroll
      for (int i = 0; i < 4; ++i) {
        int col = scol0 + 16 * i;
        ph[i] = ((const short8v*)bvh)[(size_t)(j0n + col) * 16 + sks];
        pl[i] = ((const short8v*)bvl)[(size_t)(j0n + col) * 16 + sks];
      }
    }
    const int j0 = j0beg + it * 64;
    // 4 independent accumulator chains: {hh, cross} x {ct=0, ct=1}
    f32x16 chh0 = {}, cx0 = {}, chh1 = {}, cx1 = {};
#pragma unroll
    for (int ks = 0; ks < 8; ++ks) {
      short8v bh0 = fragH[ks * 130];               // (ks*2+grp)*65 + l31
      short8v bl0 = fragL[ks * 130];
      short8v bh1 = fragH[ks * 130 + 32];          // + 32 cols (ct=1)
      short8v bl1 = fragL[ks * 130 + 32];
      chh0 = __builtin_amdgcn_mfma_f32_32x32x16_bf16(ah[ks], bh0, chh0, 0, 0, 0);
      chh1 = __builtin_amdgcn_mfma_f32_32x32x16_bf16(ah[ks], bh1, chh1, 0, 0, 0);
      cx0  = __builtin_amdgcn_mfma_f32_32x32x16_bf16(ah[ks], bl0, cx0, 0, 0, 0);
      cx1  = __builtin_amdgcn_mfma_f32_32x32x16_bf16(ah[ks], bl1, cx1, 0, 0, 0);
      cx0  = __builtin_amdgcn_mfma_f32_32x32x16_bf16(al[ks], bh0, cx0, 0, 0, 0);
      cx1  = __builtin_amdgcn_mfma_f32_32x32x16_bf16(al[ks], bh1, cx1, 0, 0, 0);
    }
    if constexpr (PASS == 1) {
#pragma unroll
      for (int r = 0; r < 16; ++r)
        rmx[r] = fmaxf(rmx[r], fmaxf(chh0[r] + cx0[r], chh1[r] + cx1[r]));
    } else {
      bool any = false;
#pragma unroll
      for (int r = 0; r < 16; ++r)
        any = any || (chh0[r] + cx0[r] >= thr[r]) || (chh1[r] + cx1[r] >= thr[r]);
      if (__any((int)any)) {                       // rare: exact re-eval path
#pragma unroll
        for (int r = 0; r < 16; ++r) {
          const int row = row0 + wave * 32 + (r & 3) + 8 * (r >> 2) + 4 * grp;
          if (chh0[r] + cx0[r] >= thr[r])
            exact_commit(ovf + (size_t)row * 128,
                         opf + (size_t)(j0 + l31) * 128, j0 + l31, &best[row]);
          if (chh1[r] + cx1[r] >= thr[r])
            exact_commit(ovf + (size_t)row * 128,
                         opf + (size_t)(j0 + 32 + l31) * 128, j0 + 32 + l31,
                         &best[row]);
        }
      }
    }
  }

  if constexpr (PASS == 1) {
    // butterfly fmax across the 32 column-lanes, then one atomic per row
#pragma unroll
    for (int mm = 1; mm <= 16; mm <<= 1) {
#pragma unroll
      for (int r = 0; r < 16; ++r) rmx[r] = fmaxf(rmx[r], __shfl_xor(rmx[r], mm));
    }
    if (l31 == 0) {
#pragma unroll
      for (int r = 0; r < 16; ++r) {
        const int row = row0 + wave * 32 + (r & 3) + 8 * (r >> 2) + 4 * grp;
        atomicMax(&rowmax[row], fenc(rmx[r]));
      }
    }
  }
}

// ----------------------- gather + layer8 + W9 (batched) --------------------
__global__ __launch_bounds__(256) void k_oc(
    const float* __restrict__ ovn, const float* __restrict__ opn,
    const unsigned long long* __restrict__ best, int n,
    const float* __restrict__ W8, const float* __restrict__ b8,
    const float* __restrict__ g8, const float* __restrict__ be8,
    const float* __restrict__ W9, const float* __restrict__ b9,
    float* __restrict__ oc)
{
  __shared__ float Y[WPB][PB][260];     // YXS rows (33.3 KB)
  const int wave = threadIdx.x >> 6, lane = threadIdx.x & 63;
  const int gw = blockIdx.x * WPB + wave;
  const int nw = gridDim.x * WPB;
  const int nb = n / PB;
  const float w9l = W9[lane], b90 = b9[0];
  const float b8l = b8[lane], g8l = g8[lane], be8l = be8[lane];
  const float* w = W8 + (size_t)lane * 257;
  for (int bt = gw; bt < nb; bt += nw) {
    const int p0 = bt * PB;
#pragma unroll
    for (int pb = 0; pb < PB; ++pb) {
      const int p = p0 + pb;
      unsigned long long v = best[p];
      int j = (int)(0xFFFFFFFFu - (unsigned)(v & 0xFFFFFFFFu));
      float Sv = fdec((unsigned)(v >> 32));
      Y[wave][pb][lane]       = ovn[(size_t)p * 128 + lane];
      Y[wave][pb][64 + lane]  = ovn[(size_t)p * 128 + 64 + lane];
      Y[wave][pb][128 + lane] = opn[(size_t)j * 128 + lane];
      Y[wave][pb][192 + lane] = opn[(size_t)j * 128 + 64 + lane];
      if (lane == 0) Y[wave][pb][256] = Sv;
    }
    __syncthreads();
    // layer8: 257 -> 64, batched over PB points; W8 rows are 257-strided
    // (1028 B, not 16B-aligned) -> scalar weight loads, float4 LDS reads.
    float acc[PB];
#pragma unroll
    for (int pb = 0; pb < PB; ++pb) acc[pb] = b8l;
#pragma unroll 2
    for (int k4 = 0; k4 < 64; ++k4) {
      const float w0 = w[k4 * 4], w1 = w[k4 * 4 + 1];
      const float w2 = w[k4 * 4 + 2], w3 = w[k4 * 4 + 3];
#pragma unroll
      for (int pb = 0; pb < PB; ++pb) {
        float4 v = reinterpret_cast<const float4*>(&Y[wave][pb][0])[k4];
        acc[pb] += w0 * v.x + w1 * v.y + w2 * v.z + w3 * v.w;
      }
    }
    {
      const float w256 = w[256];
#pragma unroll
      for (int pb = 0; pb < PB; ++pb) acc[pb] += w256 * Y[wave][pb][256];
    }
#pragma unroll
    for (int pb = 0; pb < PB; ++pb) {
      float a = acc[pb];
      a = a >= 0.f ? a : 0.2f * a;
      float s1 = rsum32(a), s2 = rsum32(a * a);
      float mu = s1 * (1.f / 32.f);
      float var = s2 * (1.f / 32.f) - mu * mu;
      float r = rsqrtf(var + 1e-5f);
      float y = (a - mu) * r * g8l + be8l;
      float tot = rsum64(y * w9l);
      if (lane == 0) oc[p0 + pb] = tot + b90;
    }
    __syncthreads();
  }
}

// ---------------------------------------------------------------------------
extern "C" void kernel_launch(void* const* d_in, const int* in_sizes, int n_in,
                              void* d_out, int out_size, void* d_ws, size_t ws_size,
                              hipStream_t stream)
{
  (void)n_in; (void)out_size; (void)ws_size;
  const float* vtx = (const float*)d_in[0];
  const float* pts = (const float*)d_in[1];
  const float* W1 = (const float*)d_in[2];  const float* b1 = (const float*)d_in[3];
  const float* g1 = (const float*)d_in[4];  const float* be1 = (const float*)d_in[5];
  const float* W2 = (const float*)d_in[6];  const float* b2 = (const float*)d_in[7];
  const float* g2 = (const float*)d_in[8];  const float* be2 = (const float*)d_in[9];
  const float* W3 = (const float*)d_in[10]; const float* b3 = (const float*)d_in[11];
  const float* g3 = (const float*)d_in[12]; const float* be3 = (const float*)d_in[13];
  const float* W4 = (const float*)d_in[14]; const float* b4 = (const float*)d_in[15];
  const float* g4 = (const float*)d_in[16]; const float* be4 = (const float*)d_in[17];
  const float* W5 = (const float*)d_in[18]; const float* b5 = (const float*)d_in[19];
  const float* g5 = (const float*)d_in[20]; const float* be5 = (const float*)d_in[21];
  const float* W6 = (const float*)d_in[22]; const float* b6 = (const float*)d_in[23];
  const float* g6 = (const float*)d_in[24]; const float* be6 = (const float*)d_in[25];
  const float* W7 = (const float*)d_in[26]; const float* b7 = (const float*)d_in[27];
  const float* W8 = (const float*)d_in[28]; const float* b8 = (const float*)d_in[29];
  const float* g8 = (const float*)d_in[30]; const float* be8 = (const float*)d_in[31];
  const float* W9 = (const float*)d_in[32]; const float* b9 = (const float*)d_in[33];

  const int n = in_sizes[0] / 3;   // 16384
  const int m = in_sizes[1] / 3;   // 16384

  // ---- workspace layout (bytes) ----
  // f_v @ 0 (n*128*4); f_p @ f_v_end (m*128*4; ovh/ovl alias it once consumed)
  // oph @ f_p_end (m*128*2); opl next (m*128*2); then g_v/g_p, best, rmax
  char* wsb = (char*)d_ws;
  float* f_v = (float*)wsb;
  size_t f_v_bytes = (size_t)n * 128 * 4;
  float* f_p = (float*)(wsb + f_v_bytes);
  size_t f_p_bytes = (size_t)m * 128 * 4;
  ushort_t* ovh = (ushort_t*)(wsb + f_v_bytes);                       // alias f_p
  ushort_t* ovl = (ushort_t*)(wsb + f_v_bytes + (size_t)n * 128 * 2); // alias f_p
  ushort_t* oph = (ushort_t*)(wsb + f_v_bytes + f_p_bytes);
  ushort_t* opl = (ushort_t*)(wsb + f_v_bytes + f_p_bytes + (size_t)m * 128 * 2);
  char* tail = wsb + f_v_bytes + f_p_bytes + (size_t)m * 128 * 4;
  unsigned* g_v = (unsigned*)tail;
  unsigned* g_p = g_v + 128;
  unsigned long long* best = (unsigned long long*)(g_p + 128);  // 8B aligned
  unsigned* rmaxv = (unsigned*)(best + n);

  float* out_ov = (float*)d_out;                 // n*128
  float* out_op = out_ov + (size_t)n * 128;      // m*128
  float* out_oc = out_op + (size_t)m * 128;      // n

  k_init<<<64, 256, 0, stream>>>(g_v, g_p, best, rmaxv, n);

  k_mlp14<<<MLP_GRID, 256, 0, stream>>>(vtx, n, W1, b1, g1, be1, W2, b2, g2, be2,
                                        W3, b3, g3, be3, W4, b4, g4, be4, f_v, g_v);
  k_mlp14<<<MLP_GRID, 256, 0, stream>>>(pts, m, W1, b1, g1, be1, W2, b2, g2, be2,
                                        W3, b3, g3, be3, W4, b4, g4, be4, f_p, g_p);

  // pts pass FIRST (f_p consumed), then vtx pass may overwrite f_p with ovh/ovl
  k_mlp57<<<MLP_GRID, 256, 0, stream>>>(f_p, g_p, m, W5, b5, g5, be5,
                                        W6, b6, g6, be6, W7, b7, out_op, oph, opl);
  k_mlp57<<<MLP_GRID, 256, 0, stream>>>(f_v, g_v, n, W5, b5, g5, be5,
                                        W6, b6, g6, be6, W7, b7, out_ov, ovh, ovl);

  const int am_grid = (n / 128) * AM_CHUNKS;
  k_amax<1><<<am_grid, 256, 0, stream>>>(ovh, ovl, oph, opl, out_ov, out_op,
                                         m, rmaxv, best);
  k_amax<2><<<am_grid, 256, 0, stream>>>(ovh, ovl, oph, opl, out_ov, out_op,
                                         m, rmaxv, best);

  k_oc<<<MLP_GRID, 256, 0, stream>>>(out_ov, out_op, best, n,
                                     W8, b8, g8, be8, W9, b9, out_oc);
}